// Round 10
// baseline (3051.270 us; speedup 1.0000x reference)
//
#include <hip/hip_runtime.h>
#include <math.h>

#define Bb 4
#define Cc 24
#define Nn 8192
#define Gg 24
#define Kk 16
#define TT 17   // top-(k+1) in fp32 reference semantics (self + 16)

// Lexicographic (dist, idx) branchless sorted insert into dl/il[TT].
#define INSERT(dd, ii)                                                         \
    if ((dd) < dl[TT - 1] || ((dd) == dl[TT - 1] && (ii) < il[TT - 1])) {      \
        _Pragma("unroll")                                                      \
        for (int u = TT - 1; u >= 1; --u) {                                    \
            bool ltp = (dd) < dl[u-1] || ((dd) == dl[u-1] && (ii) < il[u-1]);  \
            bool ltc = (dd) < dl[u]   || ((dd) == dl[u]   && (ii) < il[u]);    \
            dl[u] = ltp ? dl[u-1] : (ltc ? (dd) : dl[u]);                      \
            il[u] = ltp ? il[u-1] : (ltc ? (ii) : il[u]);                      \
        }                                                                      \
        bool lt0 = (dd) < dl[0] || ((dd) == dl[0] && (ii) < il[0]);            \
        dl[0] = lt0 ? (dd) : dl[0];                                            \
        il[0] = lt0 ? (ii) : il[0];                                            \
    }

// ---------------------------------------------------------------------------
// k_prep: transpose x -> pts_t (B,N,24); r = sum(x^2) in NUMPY PAIRWISE order:
//   squares are plain rounded muls (pts*pts materialized, never FMA-fused);
//   8 accumulators r_i = (x_i^2 + x_{i+8}^2) + x_{i+16}^2;
//   combine ((r0+r1)+(r2+r3)) + ((r4+r5)+(r6+r7)).
// Also copies center channels 72..95 of out.
// ---------------------------------------------------------------------------
__global__ __launch_bounds__(256) void k_prep(const float* __restrict__ x,
                                              float* __restrict__ pts_t,
                                              float* __restrict__ r,
                                              float* __restrict__ out0) {
#pragma clang fp contract(off)
    int t = blockIdx.x * 256 + threadIdx.x;   // [0, B*N)
    int b = t >> 13;
    int n = t & (Nn - 1);
    float v[Cc];
#pragma unroll
    for (int c = 0; c < Cc; ++c) {
        float w = x[((size_t)b * Cc + c) * Nn + n];
        v[c] = w;
        out0[((size_t)b * 96 + 72 + c) * Nn + n] = w;   // center channels
    }
    float s[Cc];
#pragma unroll
    for (int c = 0; c < Cc; ++c) s[c] = v[c] * v[c];    // rounded squares
    float p[8];
#pragma unroll
    for (int i = 0; i < 8; ++i) p[i] = (s[i] + s[i + 8]) + s[i + 16];
    float acc = ((p[0] + p[1]) + (p[2] + p[3])) + ((p[4] + p[5]) + (p[6] + p[7]));
    r[t] = acc;
#pragma unroll
    for (int c = 0; c < Cc; ++c) pts_t[(size_t)t * Cc + c] = v[c];
}

// ---------------------------------------------------------------------------
// k_knn: fp32 REFERENCE-SEMANTICS distances.
//   dot  = serial ascending-K fp32 FMA chain (BLAS K-loop shape)
//   D    = (rq - 2*dot) + r_j   (contract off, elementwise order as written)
//   rank = fp32 top-17 per half, lexicographic (D, idx) ties; merge halves;
//   drop rank 0 (self). No fp64 anywhere.
// ---------------------------------------------------------------------------
__global__ __launch_bounds__(256) void k_knn(const float* __restrict__ pts_t,
                                             const float* __restrict__ rr,
                                             int* __restrict__ idx_out,
                                             float* __restrict__ idxf_out) {
#pragma clang fp contract(off)
    __shared__ float sd[256][TT];
    __shared__ int   si[256][TT];

    const int b     = blockIdx.x >> 6;     // 64 query-tiles per batch
    const int qtile = blockIdx.x & 63;
    const int t     = threadIdx.x;
    const int ql    = t & 127;
    const int h     = t >> 7;              // candidate half (wave-uniform)
    const int qid   = qtile * 128 + ql;

    const float* qp = pts_t + ((size_t)b * Nn + qid) * Cc;
    float q[Cc];
#pragma unroll
    for (int i = 0; i < 6; ++i) {
        float4 f = ((const float4*)qp)[i];
        q[4 * i + 0] = f.x; q[4 * i + 1] = f.y;
        q[4 * i + 2] = f.z; q[4 * i + 3] = f.w;
    }
    const float rq = rr[b * Nn + qid];

    float dl[TT];
    int   il[TT];
#pragma unroll
    for (int i = 0; i < TT; ++i) { dl[i] = 3.4028235e38f; il[i] = 0x7fffffff; }

    const int    jbase = __builtin_amdgcn_readfirstlane(h * (Nn / 2));
    const float* cbase = pts_t + (size_t)b * Nn * Cc;
    const float* rbase = rr + b * Nn;

    // ILP-2: candidates j and j+2048 (independent serial FMA chains).
    for (int j = 0; j < Nn / 4; ++j) {
        const int jA = jbase + j;
        const int jB = jbase + (Nn / 4) + j;
        const float* cpA = cbase + (size_t)jA * Cc;   // wave-uniform -> s_load
        const float* cpB = cbase + (size_t)jB * Cc;
        float dotA = 0.f, dotB = 0.f;
#pragma unroll
        for (int c = 0; c < Cc; ++c) {
            dotA = fmaf(cpA[c], q[c], dotA);   // serial ascending K
            dotB = fmaf(cpB[c], q[c], dotB);
        }
        float DA = (rq - 2.0f * dotA) + rbase[jA];
        float DB = (rq - 2.0f * dotB) + rbase[jB];
        INSERT(DA, jA);
        INSERT(DB, jB);
    }

#pragma unroll
    for (int i = 0; i < TT; ++i) { sd[t][i] = dl[i]; si[t][i] = il[i]; }
    __syncthreads();

    if (h == 0) {
        // merge half-0 list [ql] with half-1 list [ql+128]; rank 0 = self.
        int ia = 0, ib = 0;
        const int outbase = (b * Nn + qid) * Kk;
        for (int rk = 0; rk < TT; ++rk) {
            float da = sd[ql][ia],       db = sd[ql + 128][ib];
            int   na = si[ql][ia],       nb = si[ql + 128][ib];
            bool takeA = (da < db) || (da == db && na < nb);
            int sel = takeA ? na : nb;
            if (takeA) ++ia; else ++ib;
            if (rk >= 1) {
                idx_out[outbase + rk - 1]  = sel;
                idxf_out[outbase + rk - 1] = (float)sel;
            }
        }
    }
}

// ---------------------------------------------------------------------------
// k_edge: thread = (point, k). Fused 3-layer 1x1-conv MLP over edge features,
// then max over k via 16-lane shuffles. (Passed correctness in round 3.)
// ---------------------------------------------------------------------------
__global__ __launch_bounds__(256) void k_edge(const float* __restrict__ pts_t,
                                              const int* __restrict__ idx_in,
                                              const float* __restrict__ W0,
                                              const float* __restrict__ b0,
                                              const float* __restrict__ W1,
                                              const float* __restrict__ b1,
                                              const float* __restrict__ W2,
                                              const float* __restrict__ b2,
                                              float* __restrict__ out0) {
    const int t  = threadIdx.x;
    const int k  = t & 15;
    const int pt = t >> 4;
    const int b     = blockIdx.x >> 9;     // 512 n-tiles of 16 points
    const int ntile = blockIdx.x & 511;
    const int n     = ntile * 16 + pt;

    const int nid = idx_in[((size_t)b * Nn + n) * Kk + k];

    float c[Cc], dlt[Cc];
    const float4* cp  = (const float4*)(pts_t + ((size_t)b * Nn + n) * Cc);
    const float4* npp = (const float4*)(pts_t + ((size_t)b * Nn + nid) * Cc);
#pragma unroll
    for (int i = 0; i < 6; ++i) {
        float4 f = cp[i];
        c[4 * i + 0] = f.x; c[4 * i + 1] = f.y; c[4 * i + 2] = f.z; c[4 * i + 3] = f.w;
    }
#pragma unroll
    for (int i = 0; i < 6; ++i) {
        float4 f = npp[i];
        dlt[4 * i + 0] = f.x - c[4 * i + 0];
        dlt[4 * i + 1] = f.y - c[4 * i + 1];
        dlt[4 * i + 2] = f.z - c[4 * i + 2];
        dlt[4 * i + 3] = f.w - c[4 * i + 3];
    }

    float h0[Gg];
#pragma unroll
    for (int o = 0; o < Gg; ++o) {
        float a = b0[o];
#pragma unroll
        for (int i = 0; i < Cc; ++i) a = fmaf(W0[o * 48 + i],      c[i],   a);
#pragma unroll
        for (int i = 0; i < Cc; ++i) a = fmaf(W0[o * 48 + 24 + i], dlt[i], a);
        h0[o] = fmaxf(a, 0.f);
    }
    float h1[Gg];
#pragma unroll
    for (int o = 0; o < Gg; ++o) {
        float a = b1[o];
#pragma unroll
        for (int i = 0; i < Gg; ++i) a = fmaf(W1[o * 48 + i],      h0[i], a);
#pragma unroll
        for (int i = 0; i < Cc; ++i) a = fmaf(W1[o * 48 + 24 + i], c[i],  a);
        h1[o] = fmaxf(a, 0.f);
    }
    float h2[Gg];
#pragma unroll
    for (int o = 0; o < Gg; ++o) {
        float a = b2[o];
#pragma unroll
        for (int i = 0; i < Gg; ++i) a = fmaf(W2[o * 72 + i],      h1[i], a);
#pragma unroll
        for (int i = 0; i < Gg; ++i) a = fmaf(W2[o * 72 + 24 + i], h0[i], a);
#pragma unroll
        for (int i = 0; i < Cc; ++i) a = fmaf(W2[o * 72 + 48 + i], c[i],  a);
        h2[o] = a;   // no relu on conv2
    }

#pragma unroll
    for (int o = 0; o < Gg; ++o) {
        float v2 = h2[o], v1 = h1[o], v0 = h0[o];
#pragma unroll
        for (int off = 8; off >= 1; off >>= 1) {
            v2 = fmaxf(v2, __shfl_xor(v2, off, 16));
            v1 = fmaxf(v1, __shfl_xor(v1, off, 16));
            v0 = fmaxf(v0, __shfl_xor(v0, off, 16));
        }
        h2[o] = v2; h1[o] = v1; h0[o] = v0;
    }

    if (k == 0) {
        size_t ob = (size_t)b * 96 * Nn + n;
#pragma unroll
        for (int o = 0; o < Gg; ++o) {
            out0[ob + (size_t)(o)      * Nn] = h2[o];
            out0[ob + (size_t)(24 + o) * Nn] = h1[o];
            out0[ob + (size_t)(48 + o) * Nn] = h0[o];
        }
    }
}

// ---------------------------------------------------------------------------
extern "C" void kernel_launch(void* const* d_in, const int* in_sizes, int n_in,
                              void* d_out, int out_size, void* d_ws, size_t ws_size,
                              hipStream_t stream) {
    const float* x  = (const float*)d_in[0];
    const float* W0 = (const float*)d_in[1];
    const float* b0 = (const float*)d_in[2];
    const float* W1 = (const float*)d_in[3];
    const float* b1 = (const float*)d_in[4];
    const float* W2 = (const float*)d_in[5];
    const float* b2 = (const float*)d_in[6];
    float* out = (float*)d_out;

    // ws layout: pts_t (B*N*24 f32) | r (B*N f32) | idx_int (B*N*16 i32)
    float* pts_t = (float*)d_ws;
    float* r     = pts_t + (size_t)Bb * Nn * Cc;
    int*   idxw  = (int*)(r + (size_t)Bb * Nn);
    float* idxf  = out + (size_t)Bb * 96 * Nn;   // output 1 region (as float)

    hipLaunchKernelGGL(k_prep, dim3((Bb * Nn) / 256), dim3(256), 0, stream,
                       x, pts_t, r, out);
    hipLaunchKernelGGL(k_knn, dim3(Bb * (Nn / 128)), dim3(256), 0, stream,
                       pts_t, r, idxw, idxf);
    hipLaunchKernelGGL(k_edge, dim3(Bb * (Nn / 16)), dim3(256), 0, stream,
                       pts_t, idxw, W0, b0, W1, b1, W2, b2, out);
}

// Round 15
// 2225.058 us; speedup vs baseline: 1.3713x; 1.3713x over previous
//
#include <hip/hip_runtime.h>
#include <math.h>

#define Bb 4
#define Cc 24
#define Nn 8192
#define Gg 24
#define Kk 16
#define TT 17   // top-(k+1) in fp32 reference semantics (self + 16)
#define SS 8    // candidate segments per query (one per wave)
#define QQ 64   // queries per block

// Lexicographic (dist, idx) branchless sorted insert into dl/il[TT].
// Order-independent: final list = 17 lexicographically smallest (d,idx).
#define INSERT(dd, ii)                                                         \
    if ((dd) < dl[TT - 1] || ((dd) == dl[TT - 1] && (ii) < il[TT - 1])) {      \
        _Pragma("unroll")                                                      \
        for (int u = TT - 1; u >= 1; --u) {                                    \
            bool ltp = (dd) < dl[u-1] || ((dd) == dl[u-1] && (ii) < il[u-1]);  \
            bool ltc = (dd) < dl[u]   || ((dd) == dl[u]   && (ii) < il[u]);    \
            dl[u] = ltp ? dl[u-1] : (ltc ? (dd) : dl[u]);                      \
            il[u] = ltp ? il[u-1] : (ltc ? (ii) : il[u]);                      \
        }                                                                      \
        bool lt0 = (dd) < dl[0] || ((dd) == dl[0] && (ii) < il[0]);            \
        dl[0] = lt0 ? (dd) : dl[0];                                            \
        il[0] = lt0 ? (ii) : il[0];                                            \
    }

// ---------------------------------------------------------------------------
// k_prep: UNCHANGED semantics (passed round 10 bit-exact).
// r = numpy pairwise sum of rounded squares; transpose; center channels.
// ---------------------------------------------------------------------------
__global__ __launch_bounds__(256) void k_prep(const float* __restrict__ x,
                                              float* __restrict__ pts_t,
                                              float* __restrict__ r,
                                              float* __restrict__ out0) {
#pragma clang fp contract(off)
    int t = blockIdx.x * 256 + threadIdx.x;   // [0, B*N)
    int b = t >> 13;
    int n = t & (Nn - 1);
    float v[Cc];
#pragma unroll
    for (int c = 0; c < Cc; ++c) {
        float w = x[((size_t)b * Cc + c) * Nn + n];
        v[c] = w;
        out0[((size_t)b * 96 + 72 + c) * Nn + n] = w;   // center channels
    }
    float s[Cc];
#pragma unroll
    for (int c = 0; c < Cc; ++c) s[c] = v[c] * v[c];    // rounded squares
    float p[8];
#pragma unroll
    for (int i = 0; i < 8; ++i) p[i] = (s[i] + s[i + 8]) + s[i + 16];
    float acc = ((p[0] + p[1]) + (p[2] + p[3])) + ((p[4] + p[5]) + (p[6] + p[7]));
    r[t] = acc;
#pragma unroll
    for (int c = 0; c < Cc; ++c) pts_t[(size_t)t * Cc + c] = v[c];
}

// ---------------------------------------------------------------------------
// k_knn: SAME per-candidate arithmetic as round 10 (bit-exact), restructured
// for occupancy+ILP: 512 threads = 8 wave-uniform segments x 64 queries;
// each thread streams 1024 candidates via 4 independent serial FMA chains;
// per-segment fp32 top-17 lists merged 8-way (lexicographic) by wave 0.
// ---------------------------------------------------------------------------
__global__ __launch_bounds__(512) void k_knn(const float* __restrict__ pts_t,
                                             const float* __restrict__ rr,
                                             int* __restrict__ idx_out,
                                             float* __restrict__ idxf_out) {
#pragma clang fp contract(off)
    __shared__ float          sd[SS * QQ][TT];
    __shared__ unsigned short si[SS * QQ][TT];

    const int b     = blockIdx.x >> 7;     // 128 query-tiles per batch
    const int qtile = blockIdx.x & 127;
    const int t     = threadIdx.x;
    const int q     = t & (QQ - 1);
    const int seg   = t >> 6;              // wave-uniform (64-lane waves)
    const int qid   = qtile * QQ + q;

    const float* qp = pts_t + ((size_t)b * Nn + qid) * Cc;
    float qv[Cc];
#pragma unroll
    for (int i = 0; i < 6; ++i) {
        float4 f = ((const float4*)qp)[i];
        qv[4 * i + 0] = f.x; qv[4 * i + 1] = f.y;
        qv[4 * i + 2] = f.z; qv[4 * i + 3] = f.w;
    }
    const float rq = rr[b * Nn + qid];

    float dl[TT];
    int   il[TT];
#pragma unroll
    for (int i = 0; i < TT; ++i) { dl[i] = 3.4028235e38f; il[i] = 0x7fffffff; }

    const int    jbase = __builtin_amdgcn_readfirstlane(seg * (Nn / SS));
    const float* cbase = pts_t + (size_t)b * Nn * Cc;
    const float* rbase = rr + b * Nn;
    const int    CH    = Nn / SS / 4;      // 256 candidates per chain

    for (int j = 0; j < CH; ++j) {
        const int j0 = jbase + j;
        const int j1 = j0 + CH;
        const int j2 = j0 + 2 * CH;
        const int j3 = j0 + 3 * CH;
        const float* c0 = cbase + (size_t)j0 * Cc;   // wave-uniform -> s_load
        const float* c1 = cbase + (size_t)j1 * Cc;
        const float* c2 = cbase + (size_t)j2 * Cc;
        const float* c3 = cbase + (size_t)j3 * Cc;
        float d0 = 0.f, d1 = 0.f, d2 = 0.f, d3 = 0.f;
#pragma unroll
        for (int c = 0; c < Cc; ++c) {
            d0 = fmaf(c0[c], qv[c], d0);   // serial ascending K (bit-exact)
            d1 = fmaf(c1[c], qv[c], d1);
            d2 = fmaf(c2[c], qv[c], d2);
            d3 = fmaf(c3[c], qv[c], d3);
        }
        float D0 = (rq - 2.0f * d0) + rbase[j0];
        float D1 = (rq - 2.0f * d1) + rbase[j1];
        float D2 = (rq - 2.0f * d2) + rbase[j2];
        float D3 = (rq - 2.0f * d3) + rbase[j3];
        INSERT(D0, j0);
        INSERT(D1, j1);
        INSERT(D2, j2);
        INSERT(D3, j3);
    }

#pragma unroll
    for (int i = 0; i < TT; ++i) {
        sd[t][i] = dl[i];
        si[t][i] = (unsigned short)(il[i] & 0xffff);
    }
    __syncthreads();

    if (t < QQ) {   // wave 0: one merger per query
        int ptr[SS];
#pragma unroll
        for (int s = 0; s < SS; ++s) ptr[s] = 0;
        const int outbase = (b * Nn + qid) * Kk;
        for (int rk = 0; rk < TT; ++rk) {
            float bd = 3.4028235e38f; int bi = 0x7fffffff; int bs = 0;
#pragma unroll
            for (int s = 0; s < SS; ++s) {
                const int row = s * QQ + q;
                float ds = sd[row][ptr[s]];
                int   is = (int)si[row][ptr[s]];
                bool better = (ds < bd) || (ds == bd && is < bi);
                bd = better ? ds : bd;
                bi = better ? is : bi;
                bs = better ? s  : bs;
            }
            ++ptr[bs];
            if (rk >= 1) {                  // rank 0 = self
                idx_out[outbase + rk - 1]  = bi;
                idxf_out[outbase + rk - 1] = (float)bi;
            }
        }
    }
}

// ---------------------------------------------------------------------------
// k_edge: UNCHANGED (passed correctness; ~110 us).
// ---------------------------------------------------------------------------
__global__ __launch_bounds__(256) void k_edge(const float* __restrict__ pts_t,
                                              const int* __restrict__ idx_in,
                                              const float* __restrict__ W0,
                                              const float* __restrict__ b0,
                                              const float* __restrict__ W1,
                                              const float* __restrict__ b1,
                                              const float* __restrict__ W2,
                                              const float* __restrict__ b2,
                                              float* __restrict__ out0) {
    const int t  = threadIdx.x;
    const int k  = t & 15;
    const int pt = t >> 4;
    const int b     = blockIdx.x >> 9;     // 512 n-tiles of 16 points
    const int ntile = blockIdx.x & 511;
    const int n     = ntile * 16 + pt;

    const int nid = idx_in[((size_t)b * Nn + n) * Kk + k];

    float c[Cc], dlt[Cc];
    const float4* cp  = (const float4*)(pts_t + ((size_t)b * Nn + n) * Cc);
    const float4* npp = (const float4*)(pts_t + ((size_t)b * Nn + nid) * Cc);
#pragma unroll
    for (int i = 0; i < 6; ++i) {
        float4 f = cp[i];
        c[4 * i + 0] = f.x; c[4 * i + 1] = f.y; c[4 * i + 2] = f.z; c[4 * i + 3] = f.w;
    }
#pragma unroll
    for (int i = 0; i < 6; ++i) {
        float4 f = npp[i];
        dlt[4 * i + 0] = f.x - c[4 * i + 0];
        dlt[4 * i + 1] = f.y - c[4 * i + 1];
        dlt[4 * i + 2] = f.z - c[4 * i + 2];
        dlt[4 * i + 3] = f.w - c[4 * i + 3];
    }

    float h0[Gg];
#pragma unroll
    for (int o = 0; o < Gg; ++o) {
        float a = b0[o];
#pragma unroll
        for (int i = 0; i < Cc; ++i) a = fmaf(W0[o * 48 + i],      c[i],   a);
#pragma unroll
        for (int i = 0; i < Cc; ++i) a = fmaf(W0[o * 48 + 24 + i], dlt[i], a);
        h0[o] = fmaxf(a, 0.f);
    }
    float h1[Gg];
#pragma unroll
    for (int o = 0; o < Gg; ++o) {
        float a = b1[o];
#pragma unroll
        for (int i = 0; i < Gg; ++i) a = fmaf(W1[o * 48 + i],      h0[i], a);
#pragma unroll
        for (int i = 0; i < Cc; ++i) a = fmaf(W1[o * 48 + 24 + i], c[i],  a);
        h1[o] = fmaxf(a, 0.f);
    }
    float h2[Gg];
#pragma unroll
    for (int o = 0; o < Gg; ++o) {
        float a = b2[o];
#pragma unroll
        for (int i = 0; i < Gg; ++i) a = fmaf(W2[o * 72 + i],      h1[i], a);
#pragma unroll
        for (int i = 0; i < Gg; ++i) a = fmaf(W2[o * 72 + 24 + i], h0[i], a);
#pragma unroll
        for (int i = 0; i < Cc; ++i) a = fmaf(W2[o * 72 + 48 + i], c[i],  a);
        h2[o] = a;   // no relu on conv2
    }

#pragma unroll
    for (int o = 0; o < Gg; ++o) {
        float v2 = h2[o], v1 = h1[o], v0 = h0[o];
#pragma unroll
        for (int off = 8; off >= 1; off >>= 1) {
            v2 = fmaxf(v2, __shfl_xor(v2, off, 16));
            v1 = fmaxf(v1, __shfl_xor(v1, off, 16));
            v0 = fmaxf(v0, __shfl_xor(v0, off, 16));
        }
        h2[o] = v2; h1[o] = v1; h0[o] = v0;
    }

    if (k == 0) {
        size_t ob = (size_t)b * 96 * Nn + n;
#pragma unroll
        for (int o = 0; o < Gg; ++o) {
            out0[ob + (size_t)(o)      * Nn] = h2[o];
            out0[ob + (size_t)(24 + o) * Nn] = h1[o];
            out0[ob + (size_t)(48 + o) * Nn] = h0[o];
        }
    }
}

// ---------------------------------------------------------------------------
extern "C" void kernel_launch(void* const* d_in, const int* in_sizes, int n_in,
                              void* d_out, int out_size, void* d_ws, size_t ws_size,
                              hipStream_t stream) {
    const float* x  = (const float*)d_in[0];
    const float* W0 = (const float*)d_in[1];
    const float* b0 = (const float*)d_in[2];
    const float* W1 = (const float*)d_in[3];
    const float* b1 = (const float*)d_in[4];
    const float* W2 = (const float*)d_in[5];
    const float* b2 = (const float*)d_in[6];
    float* out = (float*)d_out;

    // ws layout: pts_t (B*N*24 f32) | r (B*N f32) | idx_int (B*N*16 i32)
    float* pts_t = (float*)d_ws;
    float* r     = pts_t + (size_t)Bb * Nn * Cc;
    int*   idxw  = (int*)(r + (size_t)Bb * Nn);
    float* idxf  = out + (size_t)Bb * 96 * Nn;   // output 1 region (as float)

    hipLaunchKernelGGL(k_prep, dim3((Bb * Nn) / 256), dim3(256), 0, stream,
                       x, pts_t, r, out);
    hipLaunchKernelGGL(k_knn, dim3(Bb * (Nn / QQ)), dim3(512), 0, stream,
                       pts_t, r, idxw, idxf);
    hipLaunchKernelGGL(k_edge, dim3(Bb * (Nn / 16)), dim3(256), 0, stream,
                       pts_t, idxw, W0, b0, W1, b1, W2, b2, out);
}